// Round 5
// baseline (156.639 us; speedup 1.0000x reference)
//
#include <hip/hip_runtime.h>

// soft max-pool 2x2/s2 via composed polynomial sign approximation.
// x: (32, 64, 112, 112) f32  ->  out: (32, 64, 56, 56) f32
// Memory-bound target: 102.8 MB read + 25.7 MB write -> ~20.4 us @ 6.3 TB/s.
//
// R5 change: persistent grid-stride kernel + 2-stage software pipeline.
//   - 2048 blocks (8/CU), __launch_bounds__(256,8) pins 32 waves/CU
//     (forces VGPR<=64; est. need ~44). Each thread processes ~6 tiles.
//   - Prefetch next tile's 2 loads BEFORE computing the current tile:
//     per-wave outstanding loads doubled during compute; no block-retire
//     concurrency bubbles (previous: 12544 one-shot blocks, each retire
//     drained the load stream).
// Findings so far (all neutral, kernel time invariant at ~25-34us est.):
//   R1: NT hints. R2: store shape/occupancy. R3/R4: load instr density.
//   => global-memory instruction pattern is NOT the limiter; testing
//   block-lifecycle/latency pipelining. If neutral again => at floor.
//
// Overflow handling: with the test's random coeffs the composed polys blow up.
// Bound analysis (|c_k| <= 8, inputs p in (0.05,0.95)):
//   leaf maxes: |d|<=0.9 -> |poly1|<=46 -> |s|<=4e12 -> |out|<=1.8e12 (clamp-free)
//   root max: clamp d to 1e4 and inter-stage y to 1e4; use CLAMPED d in the
//   product -> |out| <= ~4e32. Everything finite, no inf, no NaN.
//   In the normal regime (|values| < 1e4) this is bit-identical to reference.

#define W_IN 112
#define W_OUT 56
#define CH_IN_STRIDE (112 * 112)   // 12544
#define CH_OUT_STRIDE (56 * 56)    // 3136
#define TOTAL_TASKS (2048 * 56 * 28)   // 3,211,264 f4-chunk tasks

typedef float f4 __attribute__((ext_vector_type(4)));
typedef float f2 __attribute__((ext_vector_type(2)));

constexpr float SF     = 0.499755859375f;      // (1 - 4*0.5^13)/2 = 2047/4096
constexpr float INV_SF = 4096.0f / 2047.0f;    // exact-constant reciprocal
constexpr float DCLAMP = 1.0e4f;

__device__ __forceinline__ float horner(float x, const float c[8]) {
    float acc = c[7];
#pragma unroll
    for (int k = 6; k >= 0; --k) acc = fmaf(acc, x, c[k]);
    return acc;
}

__device__ __forceinline__ float clampd(float x) {
    return fminf(fmaxf(x, -DCLAMP), DCLAMP);   // v_med3_f32
}

// leaf max: inputs in (0,1); provably overflow-free, no clamps.
__device__ __forceinline__ float max_leaf(float a, float b,
                                          const float c0[8], const float c1[8]) {
    float d = a - b;
    float s = horner(horner(d, c0), c1);
    return (a + b + d * s) * 0.5f;
}

// root max: inputs may be huge; clamp d and inter-stage value.
__device__ __forceinline__ float max_root(float a, float b,
                                          const float c0[8], const float c1[8]) {
    float dc = clampd(a - b);
    float s  = horner(clampd(horner(dc, c0)), c1);
    return (a + b + dc * s) * 0.5f;
}

// one 2x2 window -> one output
__device__ __forceinline__ float pool1(float e0, float e1, float e2, float e3,
                                       const float c0[8], const float c1[8]) {
    float p0 = fmaf(e0, SF, 0.5f);
    float p1 = fmaf(e1, SF, 0.5f);
    float p2 = fmaf(e2, SF, 0.5f);
    float p3 = fmaf(e3, SF, 0.5f);
    float s1 = max_leaf(p0, p1, c0, c1);
    float s2 = max_leaf(p2, p3, c0, c1);
    float r  = max_root(s1, s2, c0, c1);
    return (r - 0.5f) * INV_SF;
}

// task idx -> input f4 pointer (rows 2r,2r+1, chunk j) and output f2 pointer
__device__ __forceinline__ const f4* in_addr(const float* x, int idx) {
    int j    = idx % 28;
    int rest = idx / 28;
    int r    = rest % 56;
    int nc   = rest / 56;
    return (const f4*)(x + (size_t)nc * CH_IN_STRIDE
                         + (size_t)(2 * r) * W_IN + 4 * j);
}

__device__ __forceinline__ f2* out_addr(float* out, int idx) {
    int j    = idx % 28;
    int rest = idx / 28;
    int r    = rest % 56;
    int nc   = rest / 56;
    return (f2*)(out + (size_t)nc * CH_OUT_STRIDE + (size_t)r * W_OUT + 2 * j);
}

__global__ __launch_bounds__(256, 8) void maxpool_approx_kernel(
    const float* __restrict__ x,
    const float* __restrict__ cc0,
    const float* __restrict__ cc1,
    float* __restrict__ out) {
    const int stride = gridDim.x * blockDim.x;            // 524,288
    int idx = blockIdx.x * blockDim.x + threadIdx.x;

    // coefficients: uniform address -> scalar loads; keep in regs
    float c0[8], c1[8];
#pragma unroll
    for (int k = 0; k < 8; ++k) { c0[k] = cc0[k]; c1[k] = cc1[k]; }

    const int rowf4 = W_IN / 4;   // 28 f4 per input row

    if (idx >= TOTAL_TASKS) return;   // never taken with this launch config

    // stage 0: issue loads for the first tile
    const f4* p = in_addr(x, idx);
    f4 a = p[0];
    f4 b = p[rowf4];

    for (;;) {
        int nidx = idx + stride;
        f4 a2, b2;
        bool have_next = (nidx < TOTAL_TASKS);
        if (have_next) {
            // issue next tile's loads BEFORE computing current tile:
            // HBM latency hides under the ~130-op polynomial chain
            const f4* pn = in_addr(x, nidx);
            a2 = pn[0];
            b2 = pn[rowf4];
        }

        f2 res;
        res.x = pool1(a.x, a.y, b.x, b.y, c0, c1);
        res.y = pool1(a.z, a.w, b.z, b.w, c0, c1);
        *out_addr(out, idx) = res;

        if (!have_next) break;
        a = a2; b = b2; idx = nidx;
    }
}

extern "C" void kernel_launch(void* const* d_in, const int* in_sizes, int n_in,
                              void* d_out, int out_size, void* d_ws, size_t ws_size,
                              hipStream_t stream) {
    const float* x   = (const float*)d_in[0];
    const float* cc0 = (const float*)d_in[1];
    const float* cc1 = (const float*)d_in[2];
    float* out = (float*)d_out;

    // persistent: 2048 blocks (8 per CU) x 256 threads; each thread
    // grid-strides over ~6.1 tiles of the 3,211,264 total
    int threads = 256;
    int blocks = 2048;
    maxpool_approx_kernel<<<blocks, threads, 0, stream>>>(x, cc0, cc1, out);
}